// Round 1
// baseline (9.667 us; speedup 1.0000x reference)
//
#include <hip/hip_runtime.h>

// QuantumFCL — analytic collapse of the 16-qubit RX+RX+CNOT-ring circuit.
//
// Math: state before CNOTs is a product state ⊗_w RX(x_w+θ_w)|0>, so bits are
// independent Bernoulli with E[(-1)^{y_w}] = cos(x_w+θ_w). The CNOT ring is a
// basis permutation: z_w = y_0⊕...⊕y_w (w>=1), z_0 = y_1⊕...⊕y_15.
// <Z_w> = E[(-1)^{z_w}] = product of cos(x_j+θ_j) over the XOR set.
//   out[b][0]   = prod_{j=1..15} cos(x[b][j]+θ[j])
//   out[b][w>=1] = prod_{j=0..w}  cos(x[b][j]+θ[j])

#define NQ 16
#define BATCH 512

__global__ __launch_bounds__(256) void QuantumFCL_kernel(
    const float* __restrict__ x,      // (BATCH, NQ)
    const float* __restrict__ theta,  // (NQ,)
    float* __restrict__ out)          // (BATCH, NQ)
{
    int b = blockIdx.x * blockDim.x + threadIdx.x;
    if (b >= BATCH) return;

    const float4* xv = reinterpret_cast<const float4*>(x + (size_t)b * NQ);
    const float4* tv = reinterpret_cast<const float4*>(theta);

    float c[NQ];
#pragma unroll
    for (int q = 0; q < 4; ++q) {
        float4 xq = xv[q];
        float4 tq = tv[q];
        c[4 * q + 0] = cosf(xq.x + tq.x);
        c[4 * q + 1] = cosf(xq.y + tq.y);
        c[4 * q + 2] = cosf(xq.z + tq.z);
        c[4 * q + 3] = cosf(xq.w + tq.w);
    }

    // prefix products: pref[w] = c[0]*...*c[w]
    float o[NQ];
    float p = 1.0f;
#pragma unroll
    for (int w = 0; w < NQ; ++w) {
        p *= c[w];
        o[w] = p;
    }
    // out[0] = product of c[1..15] (all except c[0])
    float q1 = 1.0f;
#pragma unroll
    for (int w = 1; w < NQ; ++w) q1 *= c[w];
    o[0] = q1;

    float4* ov = reinterpret_cast<float4*>(out + (size_t)b * NQ);
#pragma unroll
    for (int q = 0; q < 4; ++q) {
        float4 v;
        v.x = o[4 * q + 0];
        v.y = o[4 * q + 1];
        v.z = o[4 * q + 2];
        v.w = o[4 * q + 3];
        ov[q] = v;
    }
}

extern "C" void kernel_launch(void* const* d_in, const int* in_sizes, int n_in,
                              void* d_out, int out_size, void* d_ws, size_t ws_size,
                              hipStream_t stream) {
    const float* x = (const float*)d_in[0];       // (512,16) f32
    const float* theta = (const float*)d_in[1];   // (16,) f32
    float* out = (float*)d_out;                   // (512,16) f32

    dim3 block(256);
    dim3 grid((BATCH + 255) / 256);
    QuantumFCL_kernel<<<grid, block, 0, stream>>>(x, theta, out);
}